// Round 1
// baseline (407.862 us; speedup 1.0000x reference)
//
#include <hip/hip_runtime.h>
#include <hip/hip_bf16.h>
#include <stdint.h>

#define HDIM 1024
#define FDIM 1024
#define TTOK 2048
#define CAP  2048
#define MSZ  (1024*1024)

typedef __attribute__((ext_vector_type(8))) __bf16 bf16x8;
typedef __attribute__((ext_vector_type(4))) float  f32x4;

static __device__ __forceinline__ unsigned short f2bf(float v) {
  unsigned int u = __float_as_uint(v);
  u += 0x7FFF + ((u >> 16) & 1);   // RNE
  return (unsigned short)(u >> 16);
}

static __device__ __forceinline__ void gload_lds16(const void* g, void* l) {
  __builtin_amdgcn_global_load_lds(
      (const __attribute__((address_space(1))) unsigned int*)g,
      (__attribute__((address_space(3))) unsigned int*)l, 16, 0, 0);
}

// ---------------- init: zero out (incl aux), expert-8 identity list ----------
__global__ void k_init(float* __restrict__ out, int* __restrict__ counts,
                       int* __restrict__ tok_id, float* __restrict__ tok_w) {
  int i = blockIdx.x * 256 + threadIdx.x;
  if (i < TTOK * HDIM + 1) out[i] = 0.f;
  if (i < TTOK) { tok_id[8 * CAP + i] = i; tok_w[8 * CAP + i] = 1.0f; }
  if (i < 8) counts[i] = 0;
  if (i == 8) counts[8] = TTOK;
}

// ---------------- x fp32 -> bf16 ---------------------------------------------
__global__ void k_cvt_x(const float* __restrict__ x, unsigned short* __restrict__ xb) {
  int i = blockIdx.x * 256 + threadIdx.x;       // 8 elems/thread
  const float4* in4 = (const float4*)x;
  float4 f0 = in4[i * 2], f1 = in4[i * 2 + 1];
  uint4 v;
  v.x = (unsigned)f2bf(f0.x) | ((unsigned)f2bf(f0.y) << 16);
  v.y = (unsigned)f2bf(f0.z) | ((unsigned)f2bf(f0.w) << 16);
  v.z = (unsigned)f2bf(f1.x) | ((unsigned)f2bf(f1.y) << 16);
  v.w = (unsigned)f2bf(f1.z) | ((unsigned)f2bf(f1.w) << 16);
  *((uint4*)(xb + (size_t)i * 8)) = v;
}

// ---------------- weights fp32 [R][C] -> bf16 transposed [C][R] --------------
// m: 0..7 gate_e, 8 shared_gate, 9..16 up_e, 17 shared_up, 18..25 down_e, 26 shared_down
__global__ void k_transpose(const float* __restrict__ wgp, const float* __restrict__ wsg,
                            const float* __restrict__ wup, const float* __restrict__ wsu,
                            const float* __restrict__ wdp, const float* __restrict__ wsd,
                            unsigned short* __restrict__ wB) {
  int m = blockIdx.z;
  const float* src;
  if (m < 8)       src = wgp + (size_t)m * MSZ;
  else if (m == 8) src = wsg;
  else if (m < 17) src = wup + (size_t)(m - 9) * MSZ;
  else if (m == 17) src = wsu;
  else if (m < 26) src = wdp + (size_t)(m - 18) * MSZ;
  else             src = wsd;
  unsigned short* dst = wB + (size_t)m * MSZ;
  __shared__ __align__(16) unsigned short tile[64 * 72];
  int rb = blockIdx.x * 64, cb = blockIdx.y * 64;
  int tid = threadIdx.x;
  #pragma unroll
  for (int i = 0; i < 16; i++) {
    int idx = i * 256 + tid;
    int r = idx >> 6, c = idx & 63;
    tile[c * 72 + r] = f2bf(src[(size_t)(rb + r) * 1024 + cb + c]);
  }
  __syncthreads();
  #pragma unroll
  for (int i = 0; i < 2; i++) {
    int ro = (i * 256 + tid) >> 3;
    int co = (tid & 7) * 8;
    *(uint4*)(dst + (size_t)(cb + ro) * 1024 + rb + co) =
        *(const uint4*)(tile + ro * 72 + co);
  }
}

// ---------------- router: wave per token, fp32, top2 + softmax + compaction --
__global__ void k_router(const float* __restrict__ x, const float* __restrict__ wg,
                         int* __restrict__ counts, int* __restrict__ tok_id,
                         float* __restrict__ tok_w) {
  int tid = threadIdx.x;
  int t = (blockIdx.x << 2) + (tid >> 6);
  int L = tid & 63;
  const float* xr = x + (size_t)t * HDIM;
  float acc[8] = {0, 0, 0, 0, 0, 0, 0, 0};
  for (int h = L; h < HDIM; h += 64) {
    float xv = xr[h];
    const float* wr = wg + h * 8;
    #pragma unroll
    for (int e = 0; e < 8; e++) acc[e] += xv * wr[e];
  }
  #pragma unroll
  for (int e = 0; e < 8; e++) {
    float v = acc[e];
    for (int off = 32; off > 0; off >>= 1) v += __shfl_xor(v, off);
    acc[e] = v;
  }
  if (L == 0) {
    int i1 = 0; float v1 = acc[0];
    #pragma unroll
    for (int e = 1; e < 8; e++) if (acc[e] > v1) { v1 = acc[e]; i1 = e; }
    int i2 = -1; float v2 = -1e30f;
    #pragma unroll
    for (int e = 0; e < 8; e++) if (e != i1 && acc[e] > v2) { v2 = acc[e]; i2 = e; }
    float ex = __expf(v2 - v1);
    float w1 = 1.f / (1.f + ex);
    float w2 = 1.f - w1;
    int p1 = atomicAdd(&counts[i1], 1);
    tok_id[i1 * CAP + p1] = t; tok_w[i1 * CAP + p1] = w1;
    int p2 = atomicAdd(&counts[i2], 1);
    tok_id[i2 * CAP + p2] = t; tok_w[i2 * CAP + p2] = w2;
  }
}

// ---------------- GEMM1: act = silu(x@Wg) * (x@Wu), gathered rows ------------
// tile 128(M) x 64(N per output), BK=64; 4 waves 2x2; outputs g and u share A.
__global__ __launch_bounds__(256, 2) void k_gemm1(
    const unsigned short* __restrict__ xb, const unsigned short* __restrict__ wB,
    const int* __restrict__ counts, const int* __restrict__ tok_id,
    unsigned short* __restrict__ actb) {
  int e = blockIdx.z;
  int Ne = counts[e];
  int rb = blockIdx.x << 7;
  if (rb >= Ne) return;
  int nb = blockIdx.y << 6;
  const unsigned short* wg = wB + (size_t)e * MSZ;        // [F][H] bf16
  const unsigned short* wu = wB + (size_t)(9 + e) * MSZ;  // [F][H] bf16
  __shared__ __align__(16) unsigned short As[128 * 64];
  __shared__ __align__(16) unsigned short Bgs[64 * 64];
  __shared__ __align__(16) unsigned short Bus[64 * 64];
  int tid = threadIdx.x;
  int w = tid >> 6, L = tid & 63;
  int quad = L >> 4, lane15 = L & 15;
  int wr = w >> 1, wc = w & 1;
  int c8 = (L & 7) << 3;
  const int* tlist = tok_id + e * CAP + rb;
  int trow[4];
  #pragma unroll
  for (int r = 0; r < 4; r++) {
    int row = (w << 5) + (r << 3) + (L >> 3);
    trow[r] = (rb + row < Ne) ? tlist[row] : 0;
  }
  f32x4 accg[4][2], accu[4][2];
  #pragma unroll
  for (int mt = 0; mt < 4; mt++)
    #pragma unroll
    for (int nt = 0; nt < 2; nt++) {
      accg[mt][nt] = (f32x4){0.f, 0.f, 0.f, 0.f};
      accu[mt][nt] = (f32x4){0.f, 0.f, 0.f, 0.f};
    }
  for (int it = 0; it < 16; it++) {
    int k0 = it << 6;
    #pragma unroll
    for (int r = 0; r < 4; r++)
      gload_lds16(xb + (size_t)trow[r] * 1024 + k0 + c8, As + ((w << 2) + r) * 512);
    #pragma unroll
    for (int r = 0; r < 2; r++) {
      int fr = (((w << 1) + r) << 3) + (L >> 3);
      size_t go = (size_t)(nb + fr) * 1024 + k0 + c8;
      gload_lds16(wg + go, Bgs + ((w << 1) + r) * 512);
      gload_lds16(wu + go, Bus + ((w << 1) + r) * 512);
    }
    __syncthreads();
    #pragma unroll
    for (int s = 0; s < 2; s++) {
      bf16x8 a[4], bg[2], bu[2];
      int kk = (s << 5) + (quad << 3);
      #pragma unroll
      for (int mt = 0; mt < 4; mt++)
        a[mt] = *(const bf16x8*)(As + (((wr << 6) + (mt << 4) + lane15) << 6) + kk);
      #pragma unroll
      for (int nt = 0; nt < 2; nt++) {
        int rrow = ((wc << 5) + (nt << 4) + lane15) << 6;
        bg[nt] = *(const bf16x8*)(Bgs + rrow + kk);
        bu[nt] = *(const bf16x8*)(Bus + rrow + kk);
      }
      #pragma unroll
      for (int mt = 0; mt < 4; mt++)
        #pragma unroll
        for (int nt = 0; nt < 2; nt++) {
          accg[mt][nt] = __builtin_amdgcn_mfma_f32_16x16x32_bf16(a[mt], bg[nt], accg[mt][nt], 0, 0, 0);
          accu[mt][nt] = __builtin_amdgcn_mfma_f32_16x16x32_bf16(a[mt], bu[nt], accu[mt][nt], 0, 0, 0);
        }
    }
    __syncthreads();
  }
  #pragma unroll
  for (int mt = 0; mt < 4; mt++)
    #pragma unroll
    for (int nt = 0; nt < 2; nt++)
      #pragma unroll
      for (int g = 0; g < 4; g++) {
        int r = (wr << 6) + (mt << 4) + (quad << 2) + g;
        if (rb + r < Ne) {
          float gv = accg[mt][nt][g], uv = accu[mt][nt][g];
          float av = gv / (1.f + __expf(-gv)) * uv;
          int f = nb + (wc << 5) + (nt << 4) + lane15;
          actb[(size_t)(e * CAP + rb + r) * 1024 + f] = f2bf(av);
        }
      }
}

// ---------------- GEMM2: out += w_t * (act @ Wd), atomic accumulate ----------
// tile 128x128, BK=64; 4 waves 2x2 each 64x64.
__global__ __launch_bounds__(256, 2) void k_gemm2(
    const unsigned short* __restrict__ actb, const unsigned short* __restrict__ wB,
    const int* __restrict__ counts, const int* __restrict__ tok_id,
    const float* __restrict__ tok_w, float* __restrict__ out) {
  int e = blockIdx.z;
  int Ne = counts[e];
  int rb = blockIdx.x << 7;
  if (rb >= Ne) return;
  int nb = blockIdx.y << 7;
  const unsigned short* wd = wB + (size_t)(18 + e) * MSZ;  // [H][F] bf16
  __shared__ __align__(16) unsigned short As[128 * 64];
  __shared__ __align__(16) unsigned short Bs[128 * 64];
  int tid = threadIdx.x;
  int w = tid >> 6, L = tid & 63;
  int quad = L >> 4, lane15 = L & 15;
  int wr = w >> 1, wc = w & 1;
  int c8 = (L & 7) << 3;
  const unsigned short* arow = actb + (size_t)(e * CAP + rb) * 1024;
  f32x4 acc[4][4];
  #pragma unroll
  for (int mt = 0; mt < 4; mt++)
    #pragma unroll
    for (int nt = 0; nt < 4; nt++) acc[mt][nt] = (f32x4){0.f, 0.f, 0.f, 0.f};
  for (int it = 0; it < 16; it++) {
    int k0 = it << 6;
    #pragma unroll
    for (int r = 0; r < 4; r++) {
      int row = (w << 5) + (r << 3) + (L >> 3);
      gload_lds16(arow + (size_t)row * 1024 + k0 + c8, As + ((w << 2) + r) * 512);
      gload_lds16(wd + (size_t)(nb + row) * 1024 + k0 + c8, Bs + ((w << 2) + r) * 512);
    }
    __syncthreads();
    #pragma unroll
    for (int s = 0; s < 2; s++) {
      bf16x8 a[4], b[4];
      int kk = (s << 5) + (quad << 3);
      #pragma unroll
      for (int mt = 0; mt < 4; mt++)
        a[mt] = *(const bf16x8*)(As + (((wr << 6) + (mt << 4) + lane15) << 6) + kk);
      #pragma unroll
      for (int nt = 0; nt < 4; nt++)
        b[nt] = *(const bf16x8*)(Bs + (((wc << 6) + (nt << 4) + lane15) << 6) + kk);
      #pragma unroll
      for (int mt = 0; mt < 4; mt++)
        #pragma unroll
        for (int nt = 0; nt < 4; nt++)
          acc[mt][nt] = __builtin_amdgcn_mfma_f32_16x16x32_bf16(a[mt], b[nt], acc[mt][nt], 0, 0, 0);
    }
    __syncthreads();
  }
  #pragma unroll
  for (int mt = 0; mt < 4; mt++)
    #pragma unroll
    for (int nt = 0; nt < 4; nt++)
      #pragma unroll
      for (int g = 0; g < 4; g++) {
        int r = (wr << 6) + (mt << 4) + (quad << 2) + g;
        if (rb + r < Ne) {
          int t = tok_id[e * CAP + rb + r];
          float wt = tok_w[e * CAP + rb + r];
          int hc = nb + (wc << 6) + (nt << 4) + lane15;
          atomicAdd(out + (size_t)t * 1024 + hc, acc[mt][nt][g] * wt);
        }
      }
}

extern "C" void kernel_launch(void* const* d_in, const int* in_sizes, int n_in,
                              void* d_out, int out_size, void* d_ws, size_t ws_size,
                              hipStream_t stream) {
  (void)in_sizes; (void)n_in; (void)out_size; (void)ws_size;
  const float* x   = (const float*)d_in[0];
  const float* wg  = (const float*)d_in[1];
  const float* wgp = (const float*)d_in[2];
  const float* wup = (const float*)d_in[3];
  const float* wdp = (const float*)d_in[4];
  const float* wsg = (const float*)d_in[5];
  const float* wsu = (const float*)d_in[6];
  const float* wsd = (const float*)d_in[7];
  float* out = (float*)d_out;
  char* ws = (char*)d_ws;
  // ws layout (bytes): wB 27*MSZ*2 = 56623104 | xb 4194304 | actb 37748736
  //                    | tok_id 73728 | tok_w 73728 | counts 64   (~94.1 MiB)
  unsigned short* wB   = (unsigned short*)ws;
  unsigned short* xb   = (unsigned short*)(ws + 56623104);
  unsigned short* actb = (unsigned short*)(ws + 56623104 + 4194304);
  int*   tok_id = (int*)(ws + 56623104 + 4194304 + 37748736);
  float* tok_w  = (float*)(ws + 56623104 + 4194304 + 37748736 + 73728);
  int*   counts = (int*)(ws + 56623104 + 4194304 + 37748736 + 147456);

  k_init<<<8193, 256, 0, stream>>>(out, counts, tok_id, tok_w);
  k_cvt_x<<<1024, 256, 0, stream>>>(x, xb);
  k_transpose<<<dim3(16, 16, 27), 256, 0, stream>>>(wgp, wsg, wup, wsu, wdp, wsd, wB);
  k_router<<<512, 256, 0, stream>>>(x, wg, counts, tok_id, tok_w);
  k_gemm1<<<dim3(16, 16, 9), 256, 0, stream>>>(xb, wB, counts, tok_id, actb);
  k_gemm2<<<dim3(16, 8, 9), 256, 0, stream>>>(actb, wB, counts, tok_id, tok_w, out);
}

// Round 2
// 391.756 us; speedup vs baseline: 1.0411x; 1.0411x over previous
//
#include <hip/hip_runtime.h>
#include <hip/hip_bf16.h>
#include <stdint.h>

#define HDIM 1024
#define FDIM 1024
#define TTOK 2048
#define CAP  2048
#define MSZ  (1024*1024)

typedef __attribute__((ext_vector_type(8))) __bf16 bf16x8;
typedef __attribute__((ext_vector_type(4))) float  f32x4;

static __device__ __forceinline__ unsigned short f2bf(float v) {
  unsigned int u = __float_as_uint(v);
  u += 0x7FFF + ((u >> 16) & 1);   // RNE
  return (unsigned short)(u >> 16);
}

static __device__ __forceinline__ void gload_lds16(const void* g, void* l) {
  __builtin_amdgcn_global_load_lds(
      (const __attribute__((address_space(1))) unsigned int*)g,
      (__attribute__((address_space(3))) unsigned int*)l, 16, 0, 0);
}

// ---------------- init: zero out (incl aux), expert-8 identity list ----------
__global__ void k_init(float* __restrict__ out, int* __restrict__ counts,
                       int* __restrict__ tok_id, float* __restrict__ tok_w) {
  int i = blockIdx.x * 256 + threadIdx.x;
  if (i < TTOK * HDIM + 1) out[i] = 0.f;
  if (i < TTOK) { tok_id[8 * CAP + i] = i; tok_w[8 * CAP + i] = 1.0f; }
  if (i < 8) counts[i] = 0;
  if (i == 8) counts[8] = TTOK;
}

// ---------------- x fp32 -> bf16 ---------------------------------------------
__global__ void k_cvt_x(const float* __restrict__ x, unsigned short* __restrict__ xb) {
  int i = blockIdx.x * 256 + threadIdx.x;       // 8 elems/thread
  const float4* in4 = (const float4*)x;
  float4 f0 = in4[i * 2], f1 = in4[i * 2 + 1];
  uint4 v;
  v.x = (unsigned)f2bf(f0.x) | ((unsigned)f2bf(f0.y) << 16);
  v.y = (unsigned)f2bf(f0.z) | ((unsigned)f2bf(f0.w) << 16);
  v.z = (unsigned)f2bf(f1.x) | ((unsigned)f2bf(f1.y) << 16);
  v.w = (unsigned)f2bf(f1.z) | ((unsigned)f2bf(f1.w) << 16);
  *((uint4*)(xb + (size_t)i * 8)) = v;
}

// ---------------- weights fp32 [R][C] -> bf16 transposed [C][R], no LDS ------
// Each lane owns one dst row (= src column); reads 8 consecutive src rows at
// its column (coalesced across lanes), packs bf16x8, one 16B store.
// m: 0..7 gate_e, 8 shared_gate, 9..16 up_e, 17 shared_up, 18..25 down_e, 26 shared_down
__global__ __launch_bounds__(256) void k_transpose(
    const float* __restrict__ wgp, const float* __restrict__ wsg,
    const float* __restrict__ wup, const float* __restrict__ wsu,
    const float* __restrict__ wdp, const float* __restrict__ wsd,
    unsigned short* __restrict__ wB) {
  int m = blockIdx.z;
  const float* src;
  if (m < 8)       src = wgp + (size_t)m * MSZ;
  else if (m == 8) src = wsg;
  else if (m < 17) src = wup + (size_t)(m - 9) * MSZ;
  else if (m == 17) src = wsu;
  else if (m < 26) src = wdp + (size_t)(m - 18) * MSZ;
  else             src = wsd;
  unsigned short* dst = wB + (size_t)m * MSZ;
  int w = threadIdx.x >> 6, L = threadIdx.x & 63;
  int c  = blockIdx.y * 64 + L;     // src column = dst row
  int rb = blockIdx.x * 64;
  #pragma unroll
  for (int half = 0; half < 2; half++) {
    int r0 = rb + half * 32 + w * 8;
    uint4 v;
    unsigned pk[4];
    #pragma unroll
    for (int j = 0; j < 4; j++) {
      unsigned short lo = f2bf(src[(size_t)(r0 + 2 * j)     * 1024 + c]);
      unsigned short hi = f2bf(src[(size_t)(r0 + 2 * j + 1) * 1024 + c]);
      pk[j] = (unsigned)lo | ((unsigned)hi << 16);
    }
    v.x = pk[0]; v.y = pk[1]; v.z = pk[2]; v.w = pk[3];
    *(uint4*)(dst + (size_t)c * 1024 + r0) = v;
  }
}

// ---------------- router: wave per token, fp32, top2 + softmax + compaction --
__global__ void k_router(const float* __restrict__ x, const float* __restrict__ wg,
                         int* __restrict__ counts, int* __restrict__ tok_id,
                         float* __restrict__ tok_w) {
  int tid = threadIdx.x;
  int t = (blockIdx.x << 2) + (tid >> 6);
  int L = tid & 63;
  const float* xr = x + (size_t)t * HDIM;
  float acc[8] = {0, 0, 0, 0, 0, 0, 0, 0};
  for (int h = L; h < HDIM; h += 64) {
    float xv = xr[h];
    const float* wr = wg + h * 8;
    #pragma unroll
    for (int e = 0; e < 8; e++) acc[e] += xv * wr[e];
  }
  #pragma unroll
  for (int e = 0; e < 8; e++) {
    float v = acc[e];
    for (int off = 32; off > 0; off >>= 1) v += __shfl_xor(v, off);
    acc[e] = v;
  }
  if (L == 0) {
    int i1 = 0; float v1 = acc[0];
    #pragma unroll
    for (int e = 1; e < 8; e++) if (acc[e] > v1) { v1 = acc[e]; i1 = e; }
    int i2 = -1; float v2 = -1e30f;
    #pragma unroll
    for (int e = 0; e < 8; e++) if (e != i1 && acc[e] > v2) { v2 = acc[e]; i2 = e; }
    float ex = __expf(v2 - v1);
    float w1 = 1.f / (1.f + ex);
    float w2 = 1.f - w1;
    int p1 = atomicAdd(&counts[i1], 1);
    tok_id[i1 * CAP + p1] = t; tok_w[i1 * CAP + p1] = w1;
    int p2 = atomicAdd(&counts[i2], 1);
    tok_id[i2 * CAP + p2] = t; tok_w[i2 * CAP + p2] = w2;
  }
}

// LDS tile layout (both GEMMs): row-major [row][64 bf16], but 16B chunk c of
// row R holds logical (global) chunk c ^ (R&7).  Staging permutes the GLOBAL
// source chunk per lane (stays inside the same 128B row -> coalescing intact);
// global_load_lds destination stays linear as required.  Fragment reads then
// spread each quad over all 8 bank groups -> no 16-way conflicts.

// ---------------- GEMM1: act = silu(x@Wg) * (x@Wu), gathered rows ------------
// tile 128(M) x 64(N per output), BK=64; 4 waves 2x2; outputs g and u share A.
__global__ __launch_bounds__(256, 4) void k_gemm1(
    const unsigned short* __restrict__ xb, const unsigned short* __restrict__ wB,
    const int* __restrict__ counts, const int* __restrict__ tok_id,
    unsigned short* __restrict__ actb) {
  int e = blockIdx.z;
  int Ne = counts[e];
  int rb = blockIdx.x << 7;
  if (rb >= Ne) return;
  int nb = blockIdx.y << 6;
  const unsigned short* wg = wB + (size_t)e * MSZ;        // [F][H] bf16
  const unsigned short* wu = wB + (size_t)(9 + e) * MSZ;  // [F][H] bf16
  __shared__ __align__(16) unsigned short As[128 * 64];
  __shared__ __align__(16) unsigned short Bgs[64 * 64];
  __shared__ __align__(16) unsigned short Bus[64 * 64];
  int tid = threadIdx.x;
  int w = tid >> 6, L = tid & 63;
  int quad = L >> 4, lane15 = L & 15;
  int wr = w >> 1, wc = w & 1;
  int l7 = lane15 & 7;
  int sw8 = ((L & 7) ^ (L >> 3)) << 3;    // swizzled global chunk offset (elems)
  const int* tlist = tok_id + e * CAP + rb;
  int trow[4];
  #pragma unroll
  for (int r = 0; r < 4; r++) {
    int row = (w << 5) + (r << 3) + (L >> 3);
    trow[r] = (rb + row < Ne) ? tlist[row] : 0;
  }
  f32x4 accg[4][2], accu[4][2];
  #pragma unroll
  for (int mt = 0; mt < 4; mt++)
    #pragma unroll
    for (int nt = 0; nt < 2; nt++) {
      accg[mt][nt] = (f32x4){0.f, 0.f, 0.f, 0.f};
      accu[mt][nt] = (f32x4){0.f, 0.f, 0.f, 0.f};
    }
  for (int it = 0; it < 16; it++) {
    int k0 = it << 6;
    #pragma unroll
    for (int r = 0; r < 4; r++)
      gload_lds16(xb + (size_t)trow[r] * 1024 + k0 + sw8, As + ((w << 2) + r) * 512);
    #pragma unroll
    for (int r = 0; r < 2; r++) {
      int fr = (((w << 1) + r) << 3) + (L >> 3);
      size_t go = (size_t)(nb + fr) * 1024 + k0 + sw8;
      gload_lds16(wg + go, Bgs + ((w << 1) + r) * 512);
      gload_lds16(wu + go, Bus + ((w << 1) + r) * 512);
    }
    __syncthreads();
    #pragma unroll
    for (int s = 0; s < 2; s++) {
      bf16x8 a[4], bg[2], bu[2];
      int ch = (s << 2) + quad;           // logical 16B chunk 0..7
      int po = ((ch ^ l7) << 3);          // physical element offset in row
      #pragma unroll
      for (int mt = 0; mt < 4; mt++)
        a[mt] = *(const bf16x8*)(As + (((wr << 6) + (mt << 4) + lane15) << 6) + po);
      #pragma unroll
      for (int nt = 0; nt < 2; nt++) {
        int rrow = ((wc << 5) + (nt << 4) + lane15) << 6;
        bg[nt] = *(const bf16x8*)(Bgs + rrow + po);
        bu[nt] = *(const bf16x8*)(Bus + rrow + po);
      }
      #pragma unroll
      for (int mt = 0; mt < 4; mt++)
        #pragma unroll
        for (int nt = 0; nt < 2; nt++) {
          accg[mt][nt] = __builtin_amdgcn_mfma_f32_16x16x32_bf16(a[mt], bg[nt], accg[mt][nt], 0, 0, 0);
          accu[mt][nt] = __builtin_amdgcn_mfma_f32_16x16x32_bf16(a[mt], bu[nt], accu[mt][nt], 0, 0, 0);
        }
    }
    __syncthreads();
  }
  #pragma unroll
  for (int mt = 0; mt < 4; mt++)
    #pragma unroll
    for (int nt = 0; nt < 2; nt++)
      #pragma unroll
      for (int g = 0; g < 4; g++) {
        int r = (wr << 6) + (mt << 4) + (quad << 2) + g;
        if (rb + r < Ne) {
          float gv = accg[mt][nt][g], uv = accu[mt][nt][g];
          float av = gv / (1.f + __expf(-gv)) * uv;
          int f = nb + (wc << 5) + (nt << 4) + lane15;
          actb[(size_t)(e * CAP + rb + r) * 1024 + f] = f2bf(av);
        }
      }
}

// ---------------- GEMM2: out += w_t * (act @ Wd), atomic accumulate ----------
// tile 128x128, BK=64; 4 waves 2x2 each 64x64.
__global__ __launch_bounds__(256, 4) void k_gemm2(
    const unsigned short* __restrict__ actb, const unsigned short* __restrict__ wB,
    const int* __restrict__ counts, const int* __restrict__ tok_id,
    const float* __restrict__ tok_w, float* __restrict__ out) {
  int e = blockIdx.z;
  int Ne = counts[e];
  int rb = blockIdx.x << 7;
  if (rb >= Ne) return;
  int nb = blockIdx.y << 7;
  const unsigned short* wd = wB + (size_t)(18 + e) * MSZ;  // [H][F] bf16
  __shared__ __align__(16) unsigned short As[128 * 64];
  __shared__ __align__(16) unsigned short Bs[128 * 64];
  int tid = threadIdx.x;
  int w = tid >> 6, L = tid & 63;
  int quad = L >> 4, lane15 = L & 15;
  int wr = w >> 1, wc = w & 1;
  int l7 = lane15 & 7;
  int sw8 = ((L & 7) ^ (L >> 3)) << 3;
  const unsigned short* arow = actb + (size_t)(e * CAP + rb) * 1024;
  f32x4 acc[4][4];
  #pragma unroll
  for (int mt = 0; mt < 4; mt++)
    #pragma unroll
    for (int nt = 0; nt < 4; nt++) acc[mt][nt] = (f32x4){0.f, 0.f, 0.f, 0.f};
  for (int it = 0; it < 16; it++) {
    int k0 = it << 6;
    #pragma unroll
    for (int r = 0; r < 4; r++) {
      int row = (w << 5) + (r << 3) + (L >> 3);
      gload_lds16(arow + (size_t)row * 1024 + k0 + sw8, As + ((w << 2) + r) * 512);
      gload_lds16(wd + (size_t)(nb + row) * 1024 + k0 + sw8, Bs + ((w << 2) + r) * 512);
    }
    __syncthreads();
    #pragma unroll
    for (int s = 0; s < 2; s++) {
      bf16x8 a[4], b[4];
      int ch = (s << 2) + quad;
      int po = ((ch ^ l7) << 3);
      #pragma unroll
      for (int mt = 0; mt < 4; mt++)
        a[mt] = *(const bf16x8*)(As + (((wr << 6) + (mt << 4) + lane15) << 6) + po);
      #pragma unroll
      for (int nt = 0; nt < 4; nt++)
        b[nt] = *(const bf16x8*)(Bs + (((wc << 6) + (nt << 4) + lane15) << 6) + po);
      #pragma unroll
      for (int mt = 0; mt < 4; mt++)
        #pragma unroll
        for (int nt = 0; nt < 4; nt++)
          acc[mt][nt] = __builtin_amdgcn_mfma_f32_16x16x32_bf16(a[mt], b[nt], acc[mt][nt], 0, 0, 0);
    }
    __syncthreads();
  }
  #pragma unroll
  for (int mt = 0; mt < 4; mt++)
    #pragma unroll
    for (int nt = 0; nt < 4; nt++)
      #pragma unroll
      for (int g = 0; g < 4; g++) {
        int r = (wr << 6) + (mt << 4) + (quad << 2) + g;
        if (rb + r < Ne) {
          int t = tok_id[e * CAP + rb + r];
          float wt = tok_w[e * CAP + rb + r];
          int hc = nb + (wc << 6) + (nt << 4) + lane15;
          atomicAdd(out + (size_t)t * 1024 + hc, acc[mt][nt][g] * wt);
        }
      }
}

extern "C" void kernel_launch(void* const* d_in, const int* in_sizes, int n_in,
                              void* d_out, int out_size, void* d_ws, size_t ws_size,
                              hipStream_t stream) {
  (void)in_sizes; (void)n_in; (void)out_size; (void)ws_size;
  const float* x   = (const float*)d_in[0];
  const float* wg  = (const float*)d_in[1];
  const float* wgp = (const float*)d_in[2];
  const float* wup = (const float*)d_in[3];
  const float* wdp = (const float*)d_in[4];
  const float* wsg = (const float*)d_in[5];
  const float* wsu = (const float*)d_in[6];
  const float* wsd = (const float*)d_in[7];
  float* out = (float*)d_out;
  char* ws = (char*)d_ws;
  // ws layout (bytes): wB 27*MSZ*2 = 56623104 | xb 4194304 | actb 37748736
  //                    | tok_id 73728 | tok_w 73728 | counts 64   (~94.1 MiB)
  unsigned short* wB   = (unsigned short*)ws;
  unsigned short* xb   = (unsigned short*)(ws + 56623104);
  unsigned short* actb = (unsigned short*)(ws + 56623104 + 4194304);
  int*   tok_id = (int*)(ws + 56623104 + 4194304 + 37748736);
  float* tok_w  = (float*)(ws + 56623104 + 4194304 + 37748736 + 73728);
  int*   counts = (int*)(ws + 56623104 + 4194304 + 37748736 + 147456);

  k_init<<<8193, 256, 0, stream>>>(out, counts, tok_id, tok_w);
  k_cvt_x<<<1024, 256, 0, stream>>>(x, xb);
  k_transpose<<<dim3(16, 16, 27), 256, 0, stream>>>(wgp, wsg, wup, wsu, wdp, wsd, wB);
  k_router<<<512, 256, 0, stream>>>(x, wg, counts, tok_id, tok_w);
  k_gemm1<<<dim3(16, 16, 9), 256, 0, stream>>>(xb, wB, counts, tok_id, actb);
  k_gemm2<<<dim3(16, 8, 9), 256, 0, stream>>>(actb, wB, counts, tok_id, tok_w, out);
}